// Round 2
// baseline (134.624 us; speedup 1.0000x reference)
//
#include <hip/hip_runtime.h>
#include <hip/hip_fp16.h>

// Problem constants (from reference)
#define SPP   16
#define SH    256
#define SW    256
#define HI    1024
#define WI    1024
#define CH    3
#define BATCH 4

#define TS    16    // sensor tile = 16x16 px per block (256 threads, 1 px/thread)

// tanh via v_exp_f32; |arg| <= ~1.2 here, abs error ~1e-6 (threshold 1.7e-2).
__device__ __forceinline__ float fast_tanh(float x) {
    const float e = __expf(2.0f * x);
    return (e - 1.0f) * __builtin_amdgcn_rcpf(e + 1.0f);
}

// Direct-gather kernel: no LDS, no barrier. Each thread owns one sensor px
// and gathers the 4 bilinear corners x 3 channels for its 16 jittered
// samples straight from global. The 16 spp of a px hit a ~3x3 px
// neighborhood -> L1-cached; cross-block reuse lands in L2/L3 (entire
// input = 62 MB << 256 MB L3). All 1024 blocks co-resident -> pure
// latency-tolerant gather stream.
//
// Border algebra: xb = min(floor(gx), W-2), fx = gx - xb (reaches 1.0 at the
// border) — identical to the reference's clamp.
__global__ __launch_bounds__(256) void foveated_direct(
    const float* __restrict__ img,
    const float* __restrict__ t_ptr,
    const float* __restrict__ jitter,
    float* __restrict__ out)
{
    // XCD slab swizzle: each XCD gets 128 contiguous logical blocks
    // (keeps neighboring sensor tiles — which share image rows — on one L2).
    const int bid  = blockIdx.x;
    const int L    = (bid & 7) * 128 + (bid >> 3);
    const int b    = L >> 8;
    const int trow = (L >> 4) & 15;
    const int tcol = L & 15;

    const int th = threadIdx.x;
    const int sx = tcol * TS + (th & 15);
    const int sy = trow * TS + (th >> 4);

    const float step  = 2.0f / 256.0f;
    const float tt    = t_ptr[0];
    const float inv_s = __builtin_amdgcn_rcpf(fast_tanh(tt));

    const size_t plane = (size_t)HI * WI;
    const float* __restrict__ p0 = img + (size_t)(b * CH) * plane;
    const float* __restrict__ p1 = p0 + plane;
    const float* __restrict__ p2 = p1 + plane;

    const float px = -1.0f + sx * step;
    const float py = -1.0f + sy * step;

    float acc0 = 0.0f, acc1 = 0.0f, acc2 = 0.0f, dsum = 0.0f;

    const float2* __restrict__ jit2 = (const float2*)jitter;
    const int jbase = sy * SW + sx;

    #pragma unroll 4
    for (int sp = 0; sp < SPP; ++sp) {
        const float2 j = jit2[sp * (SH * SW) + jbase];
        const float posx = px + j.x * step;
        const float posy = py + j.y * step;

        const float thx = fast_tanh(tt * posx);
        const float thy = fast_tanh(tt * posy);
        const float ddx = tt * (1.0f - thx * thx) * inv_s;
        const float ddy = tt * (1.0f - thy * thy) * inv_s;
        const float det = ddx * ddy;

        float gx = (thx * inv_s + 1.0f) * 512.0f - 0.5f;
        float gy = (thy * inv_s + 1.0f) * 512.0f - 0.5f;
        gx = fminf(fmaxf(gx, 0.0f), (float)(WI - 1));
        gy = fminf(fmaxf(gy, 0.0f), (float)(HI - 1));

        const int xb = min((int)gx, WI - 2);
        const int yb = min((int)gy, HI - 2);
        const float fx = gx - (float)xb;
        const float fy = gy - (float)yb;

        const float w00 = (1.0f - fx) * (1.0f - fy) * det;
        const float w01 = fx * (1.0f - fy) * det;
        const float w10 = (1.0f - fx) * fy * det;
        const float w11 = fx * fy * det;
        dsum += det;

        const int i0 = yb * WI + xb;   // row yb, col xb (xb+1 in same row)
        const int i1 = i0 + WI;        // row yb+1

        // Scalar dword gathers (no alignment assumptions; compiler folds
        // the +1 / +WI into offset immediates on a shared base).
        const float a00 = p0[i0], a01 = p0[i0 + 1];
        const float a10 = p0[i1], a11 = p0[i1 + 1];
        const float b00 = p1[i0], b01 = p1[i0 + 1];
        const float b10 = p1[i1], b11 = p1[i1 + 1];
        const float c00 = p2[i0], c01 = p2[i0 + 1];
        const float c10 = p2[i1], c11 = p2[i1 + 1];

        acc0 += w00 * a00 + w01 * a01 + w10 * a10 + w11 * a11;
        acc1 += w00 * b00 + w01 * b01 + w10 * b10 + w11 * b11;
        acc2 += w00 * c00 + w01 * c01 + w10 * c10 + w11 * c11;
    }

    const float inv_d = 1.0f / dsum;
    const int pix = sy * SW + sx;
    const size_t ob = (size_t)b * CH * (SH * SW) + pix;
    out[ob]                 = acc0 * inv_d;
    out[ob + (SH * SW)]     = acc1 * inv_d;
    out[ob + 2 * (SH * SW)] = acc2 * inv_d;
}

extern "C" void kernel_launch(void* const* d_in, const int* in_sizes, int n_in,
                              void* d_out, int out_size, void* d_ws, size_t ws_size,
                              hipStream_t stream) {
    const float* img    = (const float*)d_in[0];
    const float* t      = (const float*)d_in[1];
    const float* jitter = (const float*)d_in[2];
    float* out          = (float*)d_out;

    // 4 batches x 16x16 tiles = 1024 blocks, 256 threads (1 sensor px each)
    hipLaunchKernelGGL(foveated_direct, dim3(1024), dim3(256), 0, stream,
                       img, t, jitter, out);
}

// Round 3
// 125.052 us; speedup vs baseline: 1.0765x; 1.0765x over previous
//
#include <hip/hip_runtime.h>
#include <hip/hip_fp16.h>

// Problem constants (from reference)
#define SPP   16
#define SH    256
#define SW    256
#define HI    1024
#define WI    1024
#define CH    3
#define BATCH 4

#define TS    8     // sensor tile = 8x8 px per block
#define MAXD  48    // max bbox rows/cols at t=1 for 8-px tile: 42 span +4 margin +safety
#define LSTR  49    // LDS row stride (+1 pad: odd stride -> no even-stride bank alias)
#define NTHR  128   // 2 threads per sensor px: lane pair splits the 16 spp 8/8

// tanh via v_exp_f32; |arg| <= ~1.2 here, abs error ~1e-6 (threshold 1.7e-2).
__device__ __forceinline__ float fast_tanh(float x) {
    const float e = __expf(2.0f * x);
    return (e - 1.0f) * __builtin_amdgcn_rcpf(e + 1.0f);
}

// Small-tile LDS kernel. Rationale (R2 post-mortem): scattered gathers must
// hit LDS (banked, ~6 cyc/instr) not L1/TA (~1 line/cyc, 30-60 lines per
// warped 64-lane gather). R0/R1's stall was co-residency: 16x16 tiles ->
// 62-46 KB LDS -> 2-3 blocks/CU and a 4-block/CU grid. 8x8 tiles give
// 13.8 KB LDS -> ~11 blocks/CU co-resident out of 16/CU of grid work, so
// stage/barrier/sample phases of different blocks overlap deeply.
__global__ __launch_bounds__(NTHR, 6) void foveated_tile8(
    const float* __restrict__ img,
    const float* __restrict__ t_ptr,
    const float* __restrict__ jitter,
    float* __restrict__ out)
{
    __shared__ __half2 lds_rg[MAXD * LSTR];  // 9408 B
    __shared__ __half  lds_b [MAXD * LSTR];  // 4704 B

    // XCD slab swizzle: 4096 blocks -> each XCD gets 512 contiguous logical
    // blocks (half a batch = contiguous image rows -> L2 locality).
    const int bid  = blockIdx.x;
    const int L    = (bid & 7) * 512 + (bid >> 3);
    const int b    = L >> 10;           // 1024 tiles per batch (32x32)
    const int trow = (L >> 5) & 31;
    const int tcol = L & 31;
    const int sx0  = tcol * TS;
    const int sy0  = trow * TS;

    const float step  = 2.0f / 256.0f;
    const float tt    = t_ptr[0];
    const float inv_s = __builtin_amdgcn_rcpf(fast_tanh(tt));

    // Uniform bbox of the tile's warped footprint (warp is monotone/separable).
    auto gmap = [&](float p) {
        float g = (fast_tanh(tt * p) * inv_s + 1.0f) * 512.0f - 0.5f;
        return fminf(fmaxf(g, 0.0f), 1023.0f);
    };
    const float pxmin = -1.0f + sx0 * step, pxmax = pxmin + TS * step;
    const float pymin = -1.0f + sy0 * step, pymax = pymin + TS * step;
    const int x_lo = max((int)gmap(pxmin) - 1, 0);
    const int x_hi = min((int)gmap(pxmax) + 2, WI - 1);
    const int y_lo = max((int)gmap(pymin) - 1, 0);
    const int y_hi = min((int)gmap(pymax) + 2, HI - 1);
    const int ncols = x_hi - x_lo + 1;
    const int nrows = y_hi - y_lo + 1;
    const bool fits = (ncols <= MAXD) && (nrows <= MAXD);  // always true at t=1

    const size_t plane = (size_t)HI * WI;
    const float* __restrict__ p0 = img + (size_t)(b * CH) * plane;
    const float* __restrict__ p1 = p0 + plane;
    const float* __restrict__ p2 = p1 + plane;

    const int th = threadIdx.x;
    const int h  = th & 1;    // spp half: 0 -> spp 0..7, 1 -> spp 8..15
    const int p  = th >> 1;   // pixel index within the 8x8 tile
    const int sx = sx0 + (p & 7);
    const int sy = sy0 + (p >> 3);

    const float px = -1.0f + sx * step;
    const float py = -1.0f + sy * step;

    // ---- Prefetch this lane's 8 jitter pairs BEFORE staging (issue-early:
    // their HBM latency hides under the staging loop, instead of stalling
    // each spp iteration). 16 VGPRs. ----
    const float2* __restrict__ jit2 = (const float2*)jitter;
    const int jbase = h * 8 * (SH * SW) + sy * SW + sx;
    float2 jv[8];
    #pragma unroll
    for (int k = 0; k < 8; ++k) jv[k] = jit2[k * (SH * SW) + jbase];

    float acc0 = 0.0f, acc1 = 0.0f, acc2 = 0.0f, dsum = 0.0f;

    if (fits) {
        // ---- Stage bbox -> LDS (planar fp16), coalesced global reads ----
        const int npix = nrows * ncols;
        const unsigned mdiv = (1u << 22) / (unsigned)ncols + 1u;  // i<2304: exact
        for (int i = th; i < npix; i += NTHR) {
            const int r = (int)(((unsigned)i * mdiv) >> 22);
            const int c = i - r * ncols;
            const int g = (y_lo + r) * WI + (x_lo + c);
            lds_rg[r * LSTR + c] = __floats2half2_rn(p0[g], p1[g]);
            lds_b [r * LSTR + c] = __float2half_rn(p2[g]);
        }
        __syncthreads();

        // ---- Sample this lane's 8 spp from LDS ----
        #pragma unroll 2
        for (int k = 0; k < 8; ++k) {
            const float posx = px + jv[k].x * step;
            const float posy = py + jv[k].y * step;

            const float thx = fast_tanh(tt * posx);
            const float thy = fast_tanh(tt * posy);
            const float ddx = tt * (1.0f - thx * thx) * inv_s;
            const float ddy = tt * (1.0f - thy * thy) * inv_s;
            const float det = ddx * ddy;

            float gx = (thx * inv_s + 1.0f) * 512.0f - 0.5f;
            float gy = (thy * inv_s + 1.0f) * 512.0f - 0.5f;
            gx = fminf(fmaxf(gx, 0.0f), (float)(WI - 1));
            gy = fminf(fmaxf(gy, 0.0f), (float)(HI - 1));

            const int xb = min((int)gx, WI - 2);
            const int yb = min((int)gy, HI - 2);
            const float fx = gx - (float)xb;
            const float fy = gy - (float)yb;

            const float w00 = (1.0f - fx) * (1.0f - fy) * det;
            const float w01 = fx * (1.0f - fy) * det;
            const float w10 = (1.0f - fx) * fy * det;
            const float w11 = fx * fy * det;
            dsum += det;

            const int lidx = (yb - y_lo) * LSTR + (xb - x_lo);
            const float2 f00 = __half22float2(lds_rg[lidx]);
            const float2 f01 = __half22float2(lds_rg[lidx + 1]);
            const float2 f10 = __half22float2(lds_rg[lidx + LSTR]);
            const float2 f11 = __half22float2(lds_rg[lidx + LSTR + 1]);
            const float v00 = __half2float(lds_b[lidx]);
            const float v01 = __half2float(lds_b[lidx + 1]);
            const float v10 = __half2float(lds_b[lidx + LSTR]);
            const float v11 = __half2float(lds_b[lidx + LSTR + 1]);

            acc0 += w00 * f00.x + w01 * f01.x + w10 * f10.x + w11 * f11.x;
            acc1 += w00 * f00.y + w01 * f01.y + w10 * f10.y + w11 * f11.y;
            acc2 += w00 * v00   + w01 * v01   + w10 * v10   + w11 * v11;
        }
    } else {
        // ---- Fallback: direct global gathers (never taken at t=1) ----
        #pragma unroll 2
        for (int k = 0; k < 8; ++k) {
            const float posx = px + jv[k].x * step;
            const float posy = py + jv[k].y * step;

            const float thx = fast_tanh(tt * posx);
            const float thy = fast_tanh(tt * posy);
            const float ddx = tt * (1.0f - thx * thx) * inv_s;
            const float ddy = tt * (1.0f - thy * thy) * inv_s;
            const float det = ddx * ddy;

            float gx = (thx * inv_s + 1.0f) * 512.0f - 0.5f;
            float gy = (thy * inv_s + 1.0f) * 512.0f - 0.5f;
            gx = fminf(fmaxf(gx, 0.0f), (float)(WI - 1));
            gy = fminf(fmaxf(gy, 0.0f), (float)(HI - 1));

            const int xb = min((int)gx, WI - 2);
            const int yb = min((int)gy, HI - 2);
            const float fx = gx - (float)xb;
            const float fy = gy - (float)yb;

            const float w00 = (1.0f - fx) * (1.0f - fy) * det;
            const float w01 = fx * (1.0f - fy) * det;
            const float w10 = (1.0f - fx) * fy * det;
            const float w11 = fx * fy * det;
            dsum += det;

            const int i0 = yb * WI + xb;
            const int i1 = i0 + WI;
            { const float a0 = p0[i0], a1 = p0[i0 + 1], c0 = p0[i1], c1 = p0[i1 + 1];
              acc0 += a0 * w00 + a1 * w01 + c0 * w10 + c1 * w11; }
            { const float a0 = p1[i0], a1 = p1[i0 + 1], c0 = p1[i1], c1 = p1[i1 + 1];
              acc1 += a0 * w00 + a1 * w01 + c0 * w10 + c1 * w11; }
            { const float a0 = p2[i0], a1 = p2[i0 + 1], c0 = p2[i1], c1 = p2[i1 + 1];
              acc2 += a0 * w00 + a1 * w01 + c0 * w10 + c1 * w11; }
        }
    }

    // ---- Combine spp halves across the lane pair ----
    acc0 += __shfl_xor(acc0, 1);
    acc1 += __shfl_xor(acc1, 1);
    acc2 += __shfl_xor(acc2, 1);
    dsum += __shfl_xor(dsum, 1);

    if (h == 0) {
        const float inv_d = 1.0f / dsum;
        const int pix = sy * SW + sx;
        const size_t ob = (size_t)b * CH * (SH * SW) + pix;
        out[ob]                 = acc0 * inv_d;
        out[ob + (SH * SW)]     = acc1 * inv_d;
        out[ob + 2 * (SH * SW)] = acc2 * inv_d;
    }
}

extern "C" void kernel_launch(void* const* d_in, const int* in_sizes, int n_in,
                              void* d_out, int out_size, void* d_ws, size_t ws_size,
                              hipStream_t stream) {
    const float* img    = (const float*)d_in[0];
    const float* t      = (const float*)d_in[1];
    const float* jitter = (const float*)d_in[2];
    float* out          = (float*)d_out;

    // 4 batches x 32x32 tiles of 8x8 px = 4096 blocks, 128 threads
    hipLaunchKernelGGL(foveated_tile8, dim3(4096), dim3(NTHR), 0, stream,
                       img, t, jitter, out);
}

// Round 5
// 115.631 us; speedup vs baseline: 1.1642x; 1.0815x over previous
//
#include <hip/hip_runtime.h>
#include <hip/hip_fp16.h>

// Problem constants (from reference)
#define SPP   16
#define SH    256
#define SW    256
#define HI    1024
#define WI    1024
#define CH    3
#define BATCH 4

#define TS    8     // sensor tile = 8x8 px per block
#define MAXD  48    // max bbox rows/cols at t=1 for 8-px tile: 42 span +4 margin +safety
#define LSTR  49    // LDS row stride (+1 pad: odd stride -> no even-stride bank alias)
#define NTHR  128   // 2 threads per sensor px: lane pair splits the 16 spp 8/8

// tanh via v_exp_f32; |arg| <= ~1.2 here, abs error ~1e-6 (threshold 1.7e-2).
__device__ __forceinline__ float fast_tanh(float x) {
    const float e = __expf(2.0f * x);
    return (e - 1.0f) * __builtin_amdgcn_rcpf(e + 1.0f);
}

// Small-tile LDS kernel (R3 structure) with the scratch bug fixed:
// R3's jv[8] prefetch was runtime-indexed under "#pragma unroll 2" ->
// compiler put it in scratch (WRITE_SIZE 3.6->35.9 MB, 8 scratch loads in
// the hot loop). Fully unrolling the spp loops makes every jv[k] access
// compile-time-constant -> registers (rule #20).
__global__ __launch_bounds__(NTHR, 6) void foveated_tile8(
    const float* __restrict__ img,
    const float* __restrict__ t_ptr,
    const float* __restrict__ jitter,
    float* __restrict__ out)
{
    __shared__ __half2 lds_rg[MAXD * LSTR];  // 9408 B
    __shared__ __half  lds_b [MAXD * LSTR];  // 4704 B

    // XCD slab swizzle: 4096 blocks -> each XCD gets 512 contiguous logical
    // blocks (half a batch = contiguous image rows -> L2 locality).
    const int bid  = blockIdx.x;
    const int L    = (bid & 7) * 512 + (bid >> 3);
    const int b    = L >> 10;           // 1024 tiles per batch (32x32)
    const int trow = (L >> 5) & 31;
    const int tcol = L & 31;
    const int sx0  = tcol * TS;
    const int sy0  = trow * TS;

    const float step  = 2.0f / 256.0f;
    const float tt    = t_ptr[0];
    const float inv_s = __builtin_amdgcn_rcpf(fast_tanh(tt));

    // Uniform bbox of the tile's warped footprint (warp is monotone/separable).
    auto gmap = [&](float p) {
        float g = (fast_tanh(tt * p) * inv_s + 1.0f) * 512.0f - 0.5f;
        return fminf(fmaxf(g, 0.0f), 1023.0f);
    };
    const float pxmin = -1.0f + sx0 * step, pxmax = pxmin + TS * step;
    const float pymin = -1.0f + sy0 * step, pymax = pymin + TS * step;
    const int x_lo = max((int)gmap(pxmin) - 1, 0);
    const int x_hi = min((int)gmap(pxmax) + 2, WI - 1);
    const int y_lo = max((int)gmap(pymin) - 1, 0);
    const int y_hi = min((int)gmap(pymax) + 2, HI - 1);
    const int ncols = x_hi - x_lo + 1;
    const int nrows = y_hi - y_lo + 1;
    const bool fits = (ncols <= MAXD) && (nrows <= MAXD);  // always true at t=1

    const size_t plane = (size_t)HI * WI;
    const float* __restrict__ p0 = img + (size_t)(b * CH) * plane;
    const float* __restrict__ p1 = p0 + plane;
    const float* __restrict__ p2 = p1 + plane;

    const int th = threadIdx.x;
    const int h  = th & 1;    // spp half: 0 -> spp 0..7, 1 -> spp 8..15
    const int p  = th >> 1;   // pixel index within the 8x8 tile
    const int sx = sx0 + (p & 7);
    const int sy = sy0 + (p >> 3);

    const float px = -1.0f + sx * step;
    const float py = -1.0f + sy * step;

    // ---- Prefetch this lane's 8 jitter pairs BEFORE staging (issue-early).
    // Fully-unrolled consumers below -> static indexing -> stays in VGPRs. ----
    const float2* __restrict__ jit2 = (const float2*)jitter;
    const int jbase = h * 8 * (SH * SW) + sy * SW + sx;
    float2 jv0 = jit2[0 * (SH * SW) + jbase];
    float2 jv1 = jit2[1 * (SH * SW) + jbase];
    float2 jv2 = jit2[2 * (SH * SW) + jbase];
    float2 jv3 = jit2[3 * (SH * SW) + jbase];
    float2 jv4 = jit2[4 * (SH * SW) + jbase];
    float2 jv5 = jit2[5 * (SH * SW) + jbase];
    float2 jv6 = jit2[6 * (SH * SW) + jbase];
    float2 jv7 = jit2[7 * (SH * SW) + jbase];

    float acc0 = 0.0f, acc1 = 0.0f, acc2 = 0.0f, dsum = 0.0f;

    // Per-sample body (everything in registers / LDS; jx,jy are named regs).
    auto sample_lds = [&](float jx, float jy) {
        const float posx = px + jx * step;
        const float posy = py + jy * step;

        const float thx = fast_tanh(tt * posx);
        const float thy = fast_tanh(tt * posy);
        const float ddx = tt * (1.0f - thx * thx) * inv_s;
        const float ddy = tt * (1.0f - thy * thy) * inv_s;
        const float det = ddx * ddy;

        float gx = (thx * inv_s + 1.0f) * 512.0f - 0.5f;
        float gy = (thy * inv_s + 1.0f) * 512.0f - 0.5f;
        gx = fminf(fmaxf(gx, 0.0f), (float)(WI - 1));
        gy = fminf(fmaxf(gy, 0.0f), (float)(HI - 1));

        const int xb = min((int)gx, WI - 2);
        const int yb = min((int)gy, HI - 2);
        const float fx = gx - (float)xb;
        const float fy = gy - (float)yb;

        const float w00 = (1.0f - fx) * (1.0f - fy) * det;
        const float w01 = fx * (1.0f - fy) * det;
        const float w10 = (1.0f - fx) * fy * det;
        const float w11 = fx * fy * det;
        dsum += det;

        const int lidx = (yb - y_lo) * LSTR + (xb - x_lo);
        const float2 f00 = __half22float2(lds_rg[lidx]);
        const float2 f01 = __half22float2(lds_rg[lidx + 1]);
        const float2 f10 = __half22float2(lds_rg[lidx + LSTR]);
        const float2 f11 = __half22float2(lds_rg[lidx + LSTR + 1]);
        const float v00 = __half2float(lds_b[lidx]);
        const float v01 = __half2float(lds_b[lidx + 1]);
        const float v10 = __half2float(lds_b[lidx + LSTR]);
        const float v11 = __half2float(lds_b[lidx + LSTR + 1]);

        acc0 += w00 * f00.x + w01 * f01.x + w10 * f10.x + w11 * f11.x;
        acc1 += w00 * f00.y + w01 * f01.y + w10 * f10.y + w11 * f11.y;
        acc2 += w00 * v00   + w01 * v01   + w10 * v10   + w11 * v11;
    };

    auto sample_glb = [&](float jx, float jy) {
        const float posx = px + jx * step;
        const float posy = py + jy * step;

        const float thx = fast_tanh(tt * posx);
        const float thy = fast_tanh(tt * posy);
        const float ddx = tt * (1.0f - thx * thx) * inv_s;
        const float ddy = tt * (1.0f - thy * thy) * inv_s;
        const float det = ddx * ddy;

        float gx = (thx * inv_s + 1.0f) * 512.0f - 0.5f;
        float gy = (thy * inv_s + 1.0f) * 512.0f - 0.5f;
        gx = fminf(fmaxf(gx, 0.0f), (float)(WI - 1));
        gy = fminf(fmaxf(gy, 0.0f), (float)(HI - 1));

        const int xb = min((int)gx, WI - 2);
        const int yb = min((int)gy, HI - 2);
        const float fx = gx - (float)xb;
        const float fy = gy - (float)yb;

        const float w00 = (1.0f - fx) * (1.0f - fy) * det;
        const float w01 = fx * (1.0f - fy) * det;
        const float w10 = (1.0f - fx) * fy * det;
        const float w11 = fx * fy * det;
        dsum += det;

        const int i0 = yb * WI + xb;
        const int i1 = i0 + WI;
        { const float a0 = p0[i0], a1 = p0[i0 + 1], c0 = p0[i1], c1 = p0[i1 + 1];
          acc0 += a0 * w00 + a1 * w01 + c0 * w10 + c1 * w11; }
        { const float a0 = p1[i0], a1 = p1[i0 + 1], c0 = p1[i1], c1 = p1[i1 + 1];
          acc1 += a0 * w00 + a1 * w01 + c0 * w10 + c1 * w11; }
        { const float a0 = p2[i0], a1 = p2[i0 + 1], c0 = p2[i1], c1 = p2[i1 + 1];
          acc2 += a0 * w00 + a1 * w01 + c0 * w10 + c1 * w11; }
    };

    if (fits) {
        // ---- Stage bbox -> LDS (planar fp16), coalesced global reads ----
        const int npix = nrows * ncols;
        const unsigned mdiv = (1u << 22) / (unsigned)ncols + 1u;  // i<2304: exact
        for (int i = th; i < npix; i += NTHR) {
            const int r = (int)(((unsigned)i * mdiv) >> 22);
            const int c = i - r * ncols;
            const int g = (y_lo + r) * WI + (x_lo + c);
            lds_rg[r * LSTR + c] = __floats2half2_rn(p0[g], p1[g]);
            lds_b [r * LSTR + c] = __float2half_rn(p2[g]);
        }
        __syncthreads();

        // ---- Sample this lane's 8 spp from LDS (fully unrolled) ----
        sample_lds(jv0.x, jv0.y);
        sample_lds(jv1.x, jv1.y);
        sample_lds(jv2.x, jv2.y);
        sample_lds(jv3.x, jv3.y);
        sample_lds(jv4.x, jv4.y);
        sample_lds(jv5.x, jv5.y);
        sample_lds(jv6.x, jv6.y);
        sample_lds(jv7.x, jv7.y);
    } else {
        // ---- Fallback: direct global gathers (never taken at t=1) ----
        sample_glb(jv0.x, jv0.y);
        sample_glb(jv1.x, jv1.y);
        sample_glb(jv2.x, jv2.y);
        sample_glb(jv3.x, jv3.y);
        sample_glb(jv4.x, jv4.y);
        sample_glb(jv5.x, jv5.y);
        sample_glb(jv6.x, jv6.y);
        sample_glb(jv7.x, jv7.y);
    }

    // ---- Combine spp halves across the lane pair ----
    acc0 += __shfl_xor(acc0, 1);
    acc1 += __shfl_xor(acc1, 1);
    acc2 += __shfl_xor(acc2, 1);
    dsum += __shfl_xor(dsum, 1);

    if (h == 0) {
        const float inv_d = 1.0f / dsum;
        const int pix = sy * SW + sx;
        const size_t ob = (size_t)b * CH * (SH * SW) + pix;
        out[ob]                 = acc0 * inv_d;
        out[ob + (SH * SW)]     = acc1 * inv_d;
        out[ob + 2 * (SH * SW)] = acc2 * inv_d;
    }
}

extern "C" void kernel_launch(void* const* d_in, const int* in_sizes, int n_in,
                              void* d_out, int out_size, void* d_ws, size_t ws_size,
                              hipStream_t stream) {
    const float* img    = (const float*)d_in[0];
    const float* t      = (const float*)d_in[1];
    const float* jitter = (const float*)d_in[2];
    float* out          = (float*)d_out;

    // 4 batches x 32x32 tiles of 8x8 px = 4096 blocks, 128 threads
    hipLaunchKernelGGL(foveated_tile8, dim3(4096), dim3(NTHR), 0, stream,
                       img, t, jitter, out);
}

// Round 6
// 108.075 us; speedup vs baseline: 1.2457x; 1.0699x over previous
//
#include <hip/hip_runtime.h>
#include <hip/hip_fp16.h>

// Problem constants (from reference)
#define SPP   16
#define SH    256
#define SW    256
#define HI    1024
#define WI    1024
#define CH    3
#define BATCH 4

#define TS    4     // sensor tile = 4x4 px per WAVE (wave-synchronous, no barrier)
#define MAXD  26    // max bbox at t=1 for 4-px tile: 21 px span + 4 margin + safety
#define LSTR  27    // LDS row stride in uint2 (odd -> no even-stride bank alias)
#define NTHR  128   // 2 independent waves per block (separate tiles, separate LDS)

// tanh via v_exp_f32; |arg| <= ~1.2 here, abs error ~1e-6 (threshold 1.7e-2).
__device__ __forceinline__ float fast_tanh(float x) {
    const float e = __expf(2.0f * x);
    return (e - 1.0f) * __builtin_amdgcn_rcpf(e + 1.0f);
}

// R5 post-mortem: 8x8-tile blocks measured only ~35% occupancy — WG-slot
// (~16/CU) and the per-block stage->__syncthreads->sample serialization keep
// resident waves low while staging HBM latency is exposed. This version makes
// the WAVE the unit of work: one 4x4 sensor tile per wave, bbox <= 26x26,
// RGB packed as fp16 uint2 (8 B/px, 5.6 KB/tile). Two fully independent waves
// share a block only to double the WG-slot-limited wave count; there is NO
// __syncthreads — LDS producer/consumer ordering within a wave is just
// s_waitcnt lgkmcnt(0). 14 blocks x 2 waves = 28 waves/CU target.
__global__ __launch_bounds__(NTHR, 7) void foveated_wave4(
    const float* __restrict__ img,
    const float* __restrict__ t_ptr,
    const float* __restrict__ jitter,
    float* __restrict__ out)
{
    __shared__ uint2 lds_px[2][MAXD * LSTR];  // 2 x 5616 B = 11232 B

    // XCD slab swizzle: 8192 blocks -> each XCD gets 1024 contiguous logical
    // blocks (contiguous sensor rows -> overlapping bboxes stay in one L2).
    const int bid  = blockIdx.x;
    const int Lb   = (bid & 7) * 1024 + (bid >> 3);
    const int th   = threadIdx.x;
    const int w    = th >> 6;        // which wave in the block
    const int lane = th & 63;

    const int tile = Lb * 2 + w;     // [0, 16384): 4 batches x 64x64 tiles
    const int b    = tile >> 12;
    const int rem  = tile & 4095;
    const int trow = rem >> 6;
    const int tcol = rem & 63;
    const int sx0  = tcol * TS;
    const int sy0  = trow * TS;

    const float step  = 2.0f / 256.0f;
    const float tt    = t_ptr[0];
    const float inv_s = __builtin_amdgcn_rcpf(fast_tanh(tt));

    // Uniform bbox of this wave's tile (warp is monotone/separable for t>0).
    auto gmap = [&](float p) {
        float g = (fast_tanh(tt * p) * inv_s + 1.0f) * 512.0f - 0.5f;
        return fminf(fmaxf(g, 0.0f), 1023.0f);
    };
    const float pxmin = -1.0f + sx0 * step, pxmax = pxmin + TS * step;
    const float pymin = -1.0f + sy0 * step, pymax = pymin + TS * step;
    const int x_lo = max((int)gmap(pxmin) - 1, 0);
    const int x_hi = min((int)gmap(pxmax) + 2, WI - 1);
    const int y_lo = max((int)gmap(pymin) - 1, 0);
    const int y_hi = min((int)gmap(pymax) + 2, HI - 1);
    const int ncols = x_hi - x_lo + 1;
    const int nrows = y_hi - y_lo + 1;
    const bool fits = (ncols > 0) && (nrows > 0) &&
                      (ncols <= MAXD) && (nrows <= MAXD);  // always true at t=1

    const size_t plane = (size_t)HI * WI;
    const float* __restrict__ p0 = img + (size_t)(b * CH) * plane;
    const float* __restrict__ p1 = p0 + plane;
    const float* __restrict__ p2 = p1 + plane;

    // Lane decomposition: 16 px x 4 spp-lanes. Lane q handles spp 4q..4q+3.
    const int p  = lane >> 2;        // pixel 0..15 within 4x4 tile
    const int q  = lane & 3;         // spp quarter
    const int sx = sx0 + (p & 3);
    const int sy = sy0 + (p >> 2);

    const float px = -1.0f + sx * step;
    const float py = -1.0f + sy * step;

    // ---- Prefetch this lane's 4 jitter pairs into named registers BEFORE
    // staging (issue-early; static consumers -> VGPRs, rule #20). ----
    const float2* __restrict__ jit2 = (const float2*)jitter;
    const int jbase = (q * 4) * (SH * SW) + sy * SW + sx;
    const float2 jv0 = jit2[jbase];
    const float2 jv1 = jit2[jbase + 1 * (SH * SW)];
    const float2 jv2 = jit2[jbase + 2 * (SH * SW)];
    const float2 jv3 = jit2[jbase + 3 * (SH * SW)];

    float acc0 = 0.0f, acc1 = 0.0f, acc2 = 0.0f, dsum = 0.0f;

    uint2* __restrict__ T = lds_px[w];

    auto sample_lds = [&](float jx, float jy) {
        const float posx = px + jx * step;
        const float posy = py + jy * step;

        const float thx = fast_tanh(tt * posx);
        const float thy = fast_tanh(tt * posy);
        const float ddx = tt * (1.0f - thx * thx) * inv_s;
        const float ddy = tt * (1.0f - thy * thy) * inv_s;
        const float det = ddx * ddy;

        float gx = (thx * inv_s + 1.0f) * 512.0f - 0.5f;
        float gy = (thy * inv_s + 1.0f) * 512.0f - 0.5f;
        gx = fminf(fmaxf(gx, 0.0f), (float)(WI - 1));
        gy = fminf(fmaxf(gy, 0.0f), (float)(HI - 1));

        const int xb = min((int)gx, WI - 2);
        const int yb = min((int)gy, HI - 2);
        const float fx = gx - (float)xb;
        const float fy = gy - (float)yb;

        const float w00 = (1.0f - fx) * (1.0f - fy) * det;
        const float w01 = fx * (1.0f - fy) * det;
        const float w10 = (1.0f - fx) * fy * det;
        const float w11 = fx * fy * det;
        dsum += det;

        const int lidx = (yb - y_lo) * LSTR + (xb - x_lo);
        const uint2 q00 = T[lidx];
        const uint2 q01 = T[lidx + 1];
        const uint2 q10 = T[lidx + LSTR];
        const uint2 q11 = T[lidx + LSTR + 1];

        const float2 a00 = __half22float2(*(const __half2*)&q00.x);
        const float2 b00 = __half22float2(*(const __half2*)&q00.y);
        const float2 a01 = __half22float2(*(const __half2*)&q01.x);
        const float2 b01 = __half22float2(*(const __half2*)&q01.y);
        const float2 a10 = __half22float2(*(const __half2*)&q10.x);
        const float2 b10 = __half22float2(*(const __half2*)&q10.y);
        const float2 a11 = __half22float2(*(const __half2*)&q11.x);
        const float2 b11 = __half22float2(*(const __half2*)&q11.y);

        acc0 += w00 * a00.x + w01 * a01.x + w10 * a10.x + w11 * a11.x;
        acc1 += w00 * a00.y + w01 * a01.y + w10 * a10.y + w11 * a11.y;
        acc2 += w00 * b00.x + w01 * b01.x + w10 * b10.x + w11 * b11.x;
    };

    auto sample_glb = [&](float jx, float jy) {
        const float posx = px + jx * step;
        const float posy = py + jy * step;

        const float thx = fast_tanh(tt * posx);
        const float thy = fast_tanh(tt * posy);
        const float ddx = tt * (1.0f - thx * thx) * inv_s;
        const float ddy = tt * (1.0f - thy * thy) * inv_s;
        const float det = ddx * ddy;

        float gx = (thx * inv_s + 1.0f) * 512.0f - 0.5f;
        float gy = (thy * inv_s + 1.0f) * 512.0f - 0.5f;
        gx = fminf(fmaxf(gx, 0.0f), (float)(WI - 1));
        gy = fminf(fmaxf(gy, 0.0f), (float)(HI - 1));

        const int xb = min((int)gx, WI - 2);
        const int yb = min((int)gy, HI - 2);
        const float fx = gx - (float)xb;
        const float fy = gy - (float)yb;

        const float w00 = (1.0f - fx) * (1.0f - fy) * det;
        const float w01 = fx * (1.0f - fy) * det;
        const float w10 = (1.0f - fx) * fy * det;
        const float w11 = fx * fy * det;
        dsum += det;

        const int i0 = yb * WI + xb;
        const int i1 = i0 + WI;
        { const float a0 = p0[i0], a1 = p0[i0 + 1], c0 = p0[i1], c1 = p0[i1 + 1];
          acc0 += a0 * w00 + a1 * w01 + c0 * w10 + c1 * w11; }
        { const float a0 = p1[i0], a1 = p1[i0 + 1], c0 = p1[i1], c1 = p1[i1 + 1];
          acc1 += a0 * w00 + a1 * w01 + c0 * w10 + c1 * w11; }
        { const float a0 = p2[i0], a1 = p2[i0 + 1], c0 = p2[i1], c1 = p2[i1 + 1];
          acc2 += a0 * w00 + a1 * w01 + c0 * w10 + c1 * w11; }
    };

    if (fits) {
        // ---- Stage bbox -> this wave's LDS slice (fp16 NHWC4, 8 B/px) ----
        const int npix = nrows * ncols;
        const unsigned mdiv = (1u << 22) / (unsigned)ncols + 1u;  // i<676: exact
        for (int i = lane; i < npix; i += 64) {
            const int r = (int)(((unsigned)i * mdiv) >> 22);
            const int c = i - r * ncols;
            const int g = (y_lo + r) * WI + (x_lo + c);
            union { __half2 h[2]; uint2 u; } v;
            v.h[0] = __floats2half2_rn(p0[g], p1[g]);
            v.h[1] = __floats2half2_rn(p2[g], 0.0f);
            T[r * LSTR + c] = v.u;
        }
        // Wave-synchronous LDS handoff: same wave wrote, same wave reads.
        // Just drain the DS queue — no __syncthreads, no cross-wave coupling.
        asm volatile("s_waitcnt lgkmcnt(0)" ::: "memory");
        __builtin_amdgcn_sched_barrier(0);

        // ---- Sample this lane's 4 spp from LDS (fully unrolled) ----
        sample_lds(jv0.x, jv0.y);
        sample_lds(jv1.x, jv1.y);
        sample_lds(jv2.x, jv2.y);
        sample_lds(jv3.x, jv3.y);
    } else {
        // ---- Fallback: direct global gathers (never taken at t=1) ----
        sample_glb(jv0.x, jv0.y);
        sample_glb(jv1.x, jv1.y);
        sample_glb(jv2.x, jv2.y);
        sample_glb(jv3.x, jv3.y);
    }

    // ---- Reduce the 4 spp-lanes of each pixel (lanes 4p..4p+3) ----
    acc0 += __shfl_xor(acc0, 1);  acc0 += __shfl_xor(acc0, 2);
    acc1 += __shfl_xor(acc1, 1);  acc1 += __shfl_xor(acc1, 2);
    acc2 += __shfl_xor(acc2, 1);  acc2 += __shfl_xor(acc2, 2);
    dsum += __shfl_xor(dsum, 1);  dsum += __shfl_xor(dsum, 2);

    if (q == 0) {
        const float inv_d = 1.0f / dsum;
        const int pix = sy * SW + sx;
        const size_t ob = (size_t)b * CH * (SH * SW) + pix;
        out[ob]                 = acc0 * inv_d;
        out[ob + (SH * SW)]     = acc1 * inv_d;
        out[ob + 2 * (SH * SW)] = acc2 * inv_d;
    }
}

extern "C" void kernel_launch(void* const* d_in, const int* in_sizes, int n_in,
                              void* d_out, int out_size, void* d_ws, size_t ws_size,
                              hipStream_t stream) {
    const float* img    = (const float*)d_in[0];
    const float* t      = (const float*)d_in[1];
    const float* jitter = (const float*)d_in[2];
    float* out          = (float*)d_out;

    // 16384 tiles of 4x4 px, 2 per block -> 8192 blocks x 128 threads
    hipLaunchKernelGGL(foveated_wave4, dim3(8192), dim3(NTHR), 0, stream,
                       img, t, jitter, out);
}

// Round 7
// 106.957 us; speedup vs baseline: 1.2587x; 1.0104x over previous
//
#include <hip/hip_runtime.h>
#include <hip/hip_fp16.h>

// Problem constants (from reference)
#define SPP   16
#define SH    256
#define SW    256
#define HI    1024
#define WI    1024
#define CH    3
#define BATCH 4

#define TS    4     // sensor tile = 4x4 px per WAVE (wave-synchronous, no barrier)
#define MAXD  26    // max bbox at t=1 for 4-px tile: 21 px span + bilinear + safety
#define PLN   704   // LDS plane dwords: ceil(26*26/64)*64 (pad for clamped lanes)
#define NITER 11    // PLN/64 staging issues per channel
#define NTHR  128   // 2 independent waves per block (separate tiles, separate LDS)

#define AS1C(p) ((const __attribute__((address_space(1))) void*)(p))
#define AS3(p)  ((__attribute__((address_space(3))) void*)(p))

// tanh via v_exp_f32; |arg| <= ~1.2 here, abs error ~1e-6 (threshold 1.7e-2).
__device__ __forceinline__ float fast_tanh(float x) {
    const float e = __expf(2.0f * x);
    return (e - 1.0f) * __builtin_amdgcn_rcpf(e + 1.0f);
}

// R6 post-mortem: ~38 us plateau across three geometries while all pipes idle
// and busy-work sums to ~15 us -> the exposed chain is the staging loop's
// per-iteration load->vmcnt->ds_write dependency (7-11 serial latency rounds
// per wave). This version stages via ASYNC global_load_lds (fire-and-forget
// DMA, all ~33 requests in flight, ONE vmcnt(0) drain):
//   - LDS planes are f32, PACKED at dynamic stride ncols, so bbox-linear
//     index i maps to LDS dword i — satisfying the wave-uniform-base +
//     lane*4 destination rule of global_load_lds (m104/m108).
//   - fixed trip count (NITER, clamped index) -> fully unrolled, no
//     per-iteration waits; no f32->fp16 convert pass at all.
// Wave = one 4x4 tile; 2 independent waves/block; no __syncthreads.
__global__ __launch_bounds__(NTHR, 6) void foveated_async4(
    const float* __restrict__ img,
    const float* __restrict__ t_ptr,
    const float* __restrict__ jitter,
    float* __restrict__ out)
{
    __shared__ float lds_f[2][CH][PLN];   // 2 x 3 x 704 x 4 B = 16896 B

    // XCD slab swizzle: 8192 blocks -> each XCD gets 1024 contiguous logical
    // blocks (contiguous sensor rows -> overlapping bboxes stay in one L2).
    const int bid  = blockIdx.x;
    const int Lb   = (bid & 7) * 1024 + (bid >> 3);
    const int th   = threadIdx.x;
    const int w    = th >> 6;        // which wave in the block
    const int lane = th & 63;

    const int tile = Lb * 2 + w;     // [0, 16384): 4 batches x 64x64 tiles
    const int b    = tile >> 12;
    const int rem  = tile & 4095;
    const int trow = rem >> 6;
    const int tcol = rem & 63;
    const int sx0  = tcol * TS;
    const int sy0  = trow * TS;

    const float step  = 2.0f / 256.0f;
    const float tt    = t_ptr[0];
    const float inv_s = __builtin_amdgcn_rcpf(fast_tanh(tt));

    // Uniform bbox of this wave's tile (warp is monotone/separable for t>0).
    auto gmap = [&](float p) {
        float g = (fast_tanh(tt * p) * inv_s + 1.0f) * 512.0f - 0.5f;
        return fminf(fmaxf(g, 0.0f), 1023.0f);
    };
    const float pxmin = -1.0f + sx0 * step, pxmax = pxmin + TS * step;
    const float pymin = -1.0f + sy0 * step, pymax = pymin + TS * step;
    const int x_lo = max((int)gmap(pxmin) - 1, 0);
    const int x_hi = min((int)gmap(pxmax) + 2, WI - 1);
    const int y_lo = max((int)gmap(pymin) - 1, 0);
    const int y_hi = min((int)gmap(pymax) + 2, HI - 1);
    const int ncols = x_hi - x_lo + 1;
    const int nrows = y_hi - y_lo + 1;
    const bool fits = (ncols > 0) && (nrows > 0) &&
                      (ncols <= MAXD) && (nrows <= MAXD);  // always true at t=1

    const size_t plane = (size_t)HI * WI;
    const float* __restrict__ p0 = img + (size_t)(b * CH) * plane;
    const float* __restrict__ p1 = p0 + plane;
    const float* __restrict__ p2 = p1 + plane;

    // Lane decomposition: 16 px x 4 spp-lanes. Lane q handles spp 4q..4q+3.
    const int p  = lane >> 2;        // pixel 0..15 within 4x4 tile
    const int q  = lane & 3;         // spp quarter
    const int sx = sx0 + (p & 3);
    const int sy = sy0 + (p >> 2);

    const float px = -1.0f + sx * step;
    const float py = -1.0f + sy * step;

    // ---- Prefetch this lane's 4 jitter pairs into named registers early
    // (static consumers -> VGPRs, rule #20). ----
    const float2* __restrict__ jit2 = (const float2*)jitter;
    const int jbase = (q * 4) * (SH * SW) + sy * SW + sx;
    const float2 jv0 = jit2[jbase];
    const float2 jv1 = jit2[jbase + 1 * (SH * SW)];
    const float2 jv2 = jit2[jbase + 2 * (SH * SW)];
    const float2 jv3 = jit2[jbase + 3 * (SH * SW)];

    float acc0 = 0.0f, acc1 = 0.0f, acc2 = 0.0f, dsum = 0.0f;

    float* __restrict__ P0 = &lds_f[w][0][0];
    float* __restrict__ P1 = &lds_f[w][1][0];
    float* __restrict__ P2 = &lds_f[w][2][0];

    auto sample_lds = [&](float jx, float jy) {
        const float posx = px + jx * step;
        const float posy = py + jy * step;

        const float thx = fast_tanh(tt * posx);
        const float thy = fast_tanh(tt * posy);
        const float ddx = tt * (1.0f - thx * thx) * inv_s;
        const float ddy = tt * (1.0f - thy * thy) * inv_s;
        const float det = ddx * ddy;

        float gx = (thx * inv_s + 1.0f) * 512.0f - 0.5f;
        float gy = (thy * inv_s + 1.0f) * 512.0f - 0.5f;
        gx = fminf(fmaxf(gx, 0.0f), (float)(WI - 1));
        gy = fminf(fmaxf(gy, 0.0f), (float)(HI - 1));

        const int xb = min((int)gx, WI - 2);
        const int yb = min((int)gy, HI - 2);
        const float fx = gx - (float)xb;
        const float fy = gy - (float)yb;

        const float w00 = (1.0f - fx) * (1.0f - fy) * det;
        const float w01 = fx * (1.0f - fy) * det;
        const float w10 = (1.0f - fx) * fy * det;
        const float w11 = fx * fy * det;
        dsum += det;

        // Packed planar layout: LDS index = (row)*ncols + col.
        const int lidx = (yb - y_lo) * ncols + (xb - x_lo);
        const int l01  = lidx + 1;
        const int l10  = lidx + ncols;
        const int l11  = l10 + 1;

        acc0 += w00 * P0[lidx] + w01 * P0[l01] + w10 * P0[l10] + w11 * P0[l11];
        acc1 += w00 * P1[lidx] + w01 * P1[l01] + w10 * P1[l10] + w11 * P1[l11];
        acc2 += w00 * P2[lidx] + w01 * P2[l01] + w10 * P2[l10] + w11 * P2[l11];
    };

    auto sample_glb = [&](float jx, float jy) {
        const float posx = px + jx * step;
        const float posy = py + jy * step;

        const float thx = fast_tanh(tt * posx);
        const float thy = fast_tanh(tt * posy);
        const float ddx = tt * (1.0f - thx * thx) * inv_s;
        const float ddy = tt * (1.0f - thy * thy) * inv_s;
        const float det = ddx * ddy;

        float gx = (thx * inv_s + 1.0f) * 512.0f - 0.5f;
        float gy = (thy * inv_s + 1.0f) * 512.0f - 0.5f;
        gx = fminf(fmaxf(gx, 0.0f), (float)(WI - 1));
        gy = fminf(fmaxf(gy, 0.0f), (float)(HI - 1));

        const int xb = min((int)gx, WI - 2);
        const int yb = min((int)gy, HI - 2);
        const float fx = gx - (float)xb;
        const float fy = gy - (float)yb;

        const float w00 = (1.0f - fx) * (1.0f - fy) * det;
        const float w01 = fx * (1.0f - fy) * det;
        const float w10 = (1.0f - fx) * fy * det;
        const float w11 = fx * fy * det;
        dsum += det;

        const int i0 = yb * WI + xb;
        const int i1 = i0 + WI;
        { const float a0 = p0[i0], a1 = p0[i0 + 1], c0 = p0[i1], c1 = p0[i1 + 1];
          acc0 += a0 * w00 + a1 * w01 + c0 * w10 + c1 * w11; }
        { const float a0 = p1[i0], a1 = p1[i0 + 1], c0 = p1[i1], c1 = p1[i1 + 1];
          acc1 += a0 * w00 + a1 * w01 + c0 * w10 + c1 * w11; }
        { const float a0 = p2[i0], a1 = p2[i0 + 1], c0 = p2[i1], c1 = p2[i1 + 1];
          acc2 += a0 * w00 + a1 * w01 + c0 * w10 + c1 * w11; }
    };

    if (fits) {
        // ---- Async-stage bbox -> LDS planes via global_load_lds width 4.
        // Fixed trip count, fully unrolled, clamped index: ALL requests go
        // into flight back-to-back; one vmcnt(0) drain at the end. LDS dest
        // is wave-uniform base + lane*4 (HW rule); global src is per-lane. ----
        const int npix  = nrows * ncols;
        const int niter = (npix + 63) >> 6;                     // <= NITER
        const unsigned mdiv = (1u << 22) / (unsigned)ncols + 1u; // i<2304: exact
        #pragma unroll
        for (int k = 0; k < NITER; ++k) {
            if (k < niter) {   // wave-uniform branch
                int i = k * 64 + lane;
                i = min(i, npix - 1);                 // clamp: valid addr, dup write in pad
                const int r = (int)(((unsigned)i * mdiv) >> 22);
                const int c = i - r * ncols;
                const int g = (y_lo + r) * WI + (x_lo + c);
                __builtin_amdgcn_global_load_lds(AS1C(p0 + g), AS3(P0 + k * 64), 4, 0, 0);
                __builtin_amdgcn_global_load_lds(AS1C(p1 + g), AS3(P1 + k * 64), 4, 0, 0);
                __builtin_amdgcn_global_load_lds(AS1C(p2 + g), AS3(P2 + k * 64), 4, 0, 0);
            }
        }
        // Same wave produced and consumes: a single vmcnt drain, no barrier.
        asm volatile("s_waitcnt vmcnt(0)" ::: "memory");
        __builtin_amdgcn_sched_barrier(0);

        // ---- Sample this lane's 4 spp from LDS (fully unrolled) ----
        sample_lds(jv0.x, jv0.y);
        sample_lds(jv1.x, jv1.y);
        sample_lds(jv2.x, jv2.y);
        sample_lds(jv3.x, jv3.y);
    } else {
        // ---- Fallback: direct global gathers (never taken at t=1) ----
        sample_glb(jv0.x, jv0.y);
        sample_glb(jv1.x, jv1.y);
        sample_glb(jv2.x, jv2.y);
        sample_glb(jv3.x, jv3.y);
    }

    // ---- Reduce the 4 spp-lanes of each pixel (lanes 4p..4p+3) ----
    acc0 += __shfl_xor(acc0, 1);  acc0 += __shfl_xor(acc0, 2);
    acc1 += __shfl_xor(acc1, 1);  acc1 += __shfl_xor(acc1, 2);
    acc2 += __shfl_xor(acc2, 1);  acc2 += __shfl_xor(acc2, 2);
    dsum += __shfl_xor(dsum, 1);  dsum += __shfl_xor(dsum, 2);

    if (q == 0) {
        const float inv_d = 1.0f / dsum;
        const int pix = sy * SW + sx;
        const size_t ob = (size_t)b * CH * (SH * SW) + pix;
        out[ob]                 = acc0 * inv_d;
        out[ob + (SH * SW)]     = acc1 * inv_d;
        out[ob + 2 * (SH * SW)] = acc2 * inv_d;
    }
}

extern "C" void kernel_launch(void* const* d_in, const int* in_sizes, int n_in,
                              void* d_out, int out_size, void* d_ws, size_t ws_size,
                              hipStream_t stream) {
    const float* img    = (const float*)d_in[0];
    const float* t      = (const float*)d_in[1];
    const float* jitter = (const float*)d_in[2];
    float* out          = (float*)d_out;

    // 16384 tiles of 4x4 px, 2 per block -> 8192 blocks x 128 threads
    hipLaunchKernelGGL(foveated_async4, dim3(8192), dim3(NTHR), 0, stream,
                       img, t, jitter, out);
}

// Round 8
// 105.478 us; speedup vs baseline: 1.2763x; 1.0140x over previous
//
#include <hip/hip_runtime.h>
#include <hip/hip_fp16.h>

// Problem constants (from reference)
#define SPP   16
#define SH    256
#define SW    256
#define HI    1024
#define WI    1024
#define CH    3
#define BATCH 4

#define TS    8     // sensor tile = 8x8 px per WAVE, 1 px per lane, 16 spp in-lane
#define MAXD  46    // exact max bbox at t=1: floor-diff(8px*5.2517) + 4 = 46
#define PLN   2176  // LDS plane dwords: ceil(46*46/64)*64
#define NITER 34    // PLN/64 staging issues per channel
#define NTHR  64    // one wave per block

#define AS1C(p) ((const __attribute__((address_space(1))) void*)(p))
#define AS3(p)  ((__attribute__((address_space(3))) void*)(p))

// tanh via v_exp_f32; |arg| <= ~1.2 here, abs error ~1e-6 (threshold 1.7e-2).
__device__ __forceinline__ float fast_tanh(float x) {
    const float e = __expf(2.0f * x);
    return (e - 1.0f) * __builtin_amdgcn_rcpf(e + 1.0f);
}

// R7 post-mortem: three staging schemes all plateau ~36us -> bottleneck is in
// the shared structure. Culprit found by access-pattern audit: the p*4+q lane
// split scattered each jitter load into ~64 transactions (16 planes x tiny
// runs, 512 KB apart) and forced shfl reduces. This version restores R0-style
// 1 px/lane + in-lane spp loop (coalesced jitter: 8x64B runs per load;
// contiguous stores; zero shuffles), keeps R6/R7's wave-synchronous no-barrier
// structure and R7's async global_load_lds f32 staging (one vmcnt(0) drain
// covering jitter prefetch + all 102 DMA requests). 8x8 tile per wave halves
// halo overhead vs 4x4. 16 independent spp chains give intra-wave ILP.
__global__ __launch_bounds__(NTHR, 4) void foveated_wave8(
    const float* __restrict__ img,
    const float* __restrict__ t_ptr,
    const float* __restrict__ jitter,
    float* __restrict__ out)
{
    __shared__ float lds_f[CH][PLN];   // 3 x 2176 x 4 B = 26112 B, one wave/block

    // XCD slab swizzle: 4096 blocks -> each XCD gets 512 contiguous logical
    // blocks (contiguous sensor rows -> overlapping bboxes stay in one L2).
    const int bid  = blockIdx.x;
    const int L    = (bid & 7) * 512 + (bid >> 3);
    const int b    = L >> 10;            // 1024 tiles per batch (32x32 of 8x8)
    const int rem  = L & 1023;
    const int trow = rem >> 5;
    const int tcol = rem & 31;
    const int sx0  = tcol * TS;
    const int sy0  = trow * TS;

    const int lane = threadIdx.x;        // 0..63
    const int sx   = sx0 + (lane & 7);
    const int sy   = sy0 + (lane >> 3);

    const float step  = 2.0f / 256.0f;
    const float tt    = t_ptr[0];
    const float inv_s = __builtin_amdgcn_rcpf(fast_tanh(tt));

    // Uniform bbox of this wave's tile (warp is monotone/separable for t>0).
    auto gmap = [&](float p) {
        float g = (fast_tanh(tt * p) * inv_s + 1.0f) * 512.0f - 0.5f;
        return fminf(fmaxf(g, 0.0f), 1023.0f);
    };
    const float pxmin = -1.0f + sx0 * step, pxmax = pxmin + TS * step;
    const float pymin = -1.0f + sy0 * step, pymax = pymin + TS * step;
    const int x_lo = max((int)gmap(pxmin) - 1, 0);
    const int x_hi = min((int)gmap(pxmax) + 2, WI - 1);
    const int y_lo = max((int)gmap(pymin) - 1, 0);
    const int y_hi = min((int)gmap(pymax) + 2, HI - 1);
    const int ncols = x_hi - x_lo + 1;
    const int nrows = y_hi - y_lo + 1;
    const bool fits = (ncols > 0) && (nrows > 0) &&
                      (ncols <= MAXD) && (nrows <= MAXD);  // always true at t=1

    const size_t plane = (size_t)HI * WI;
    const float* __restrict__ p0 = img + (size_t)(b * CH) * plane;
    const float* __restrict__ p1 = p0 + plane;
    const float* __restrict__ p2 = p1 + plane;

    const float px = -1.0f + sx * step;
    const float py = -1.0f + sy * step;

    // ---- Issue ALL 16 jitter loads first (coalesced: 64 consecutive px per
    // plane). Named registers, static consumers -> VGPRs (rule #20). Their
    // latency hides under the staging DMA; the single vmcnt(0) drains both. ----
    const float2* __restrict__ jit2 = (const float2*)jitter;
    const int jbase = sy * SW + sx;
    const float2 jv0  = jit2[jbase +  0 * (SH * SW)];
    const float2 jv1  = jit2[jbase +  1 * (SH * SW)];
    const float2 jv2  = jit2[jbase +  2 * (SH * SW)];
    const float2 jv3  = jit2[jbase +  3 * (SH * SW)];
    const float2 jv4  = jit2[jbase +  4 * (SH * SW)];
    const float2 jv5  = jit2[jbase +  5 * (SH * SW)];
    const float2 jv6  = jit2[jbase +  6 * (SH * SW)];
    const float2 jv7  = jit2[jbase +  7 * (SH * SW)];
    const float2 jv8  = jit2[jbase +  8 * (SH * SW)];
    const float2 jv9  = jit2[jbase +  9 * (SH * SW)];
    const float2 jv10 = jit2[jbase + 10 * (SH * SW)];
    const float2 jv11 = jit2[jbase + 11 * (SH * SW)];
    const float2 jv12 = jit2[jbase + 12 * (SH * SW)];
    const float2 jv13 = jit2[jbase + 13 * (SH * SW)];
    const float2 jv14 = jit2[jbase + 14 * (SH * SW)];
    const float2 jv15 = jit2[jbase + 15 * (SH * SW)];

    float acc0 = 0.0f, acc1 = 0.0f, acc2 = 0.0f, dsum = 0.0f;

    float* __restrict__ P0 = &lds_f[0][0];
    float* __restrict__ P1 = &lds_f[1][0];
    float* __restrict__ P2 = &lds_f[2][0];

    auto sample_lds = [&](float jx, float jy) {
        const float posx = px + jx * step;
        const float posy = py + jy * step;

        const float thx = fast_tanh(tt * posx);
        const float thy = fast_tanh(tt * posy);
        const float ddx = tt * (1.0f - thx * thx) * inv_s;
        const float ddy = tt * (1.0f - thy * thy) * inv_s;
        const float det = ddx * ddy;

        float gx = (thx * inv_s + 1.0f) * 512.0f - 0.5f;
        float gy = (thy * inv_s + 1.0f) * 512.0f - 0.5f;
        gx = fminf(fmaxf(gx, 0.0f), (float)(WI - 1));
        gy = fminf(fmaxf(gy, 0.0f), (float)(HI - 1));

        const int xb = min((int)gx, WI - 2);
        const int yb = min((int)gy, HI - 2);
        const float fx = gx - (float)xb;
        const float fy = gy - (float)yb;

        const float w00 = (1.0f - fx) * (1.0f - fy) * det;
        const float w01 = fx * (1.0f - fy) * det;
        const float w10 = (1.0f - fx) * fy * det;
        const float w11 = fx * fy * det;
        dsum += det;

        // Packed planar layout: LDS index = row*ncols + col.
        const int lidx = (yb - y_lo) * ncols + (xb - x_lo);
        const int l10  = lidx + ncols;

        acc0 += w00 * P0[lidx] + w01 * P0[lidx + 1] + w10 * P0[l10] + w11 * P0[l10 + 1];
        acc1 += w00 * P1[lidx] + w01 * P1[lidx + 1] + w10 * P1[l10] + w11 * P1[l10 + 1];
        acc2 += w00 * P2[lidx] + w01 * P2[lidx + 1] + w10 * P2[l10] + w11 * P2[l10 + 1];
    };

    auto sample_glb = [&](float jx, float jy) {
        const float posx = px + jx * step;
        const float posy = py + jy * step;

        const float thx = fast_tanh(tt * posx);
        const float thy = fast_tanh(tt * posy);
        const float ddx = tt * (1.0f - thx * thx) * inv_s;
        const float ddy = tt * (1.0f - thy * thy) * inv_s;
        const float det = ddx * ddy;

        float gx = (thx * inv_s + 1.0f) * 512.0f - 0.5f;
        float gy = (thy * inv_s + 1.0f) * 512.0f - 0.5f;
        gx = fminf(fmaxf(gx, 0.0f), (float)(WI - 1));
        gy = fminf(fmaxf(gy, 0.0f), (float)(HI - 1));

        const int xb = min((int)gx, WI - 2);
        const int yb = min((int)gy, HI - 2);
        const float fx = gx - (float)xb;
        const float fy = gy - (float)yb;

        const float w00 = (1.0f - fx) * (1.0f - fy) * det;
        const float w01 = fx * (1.0f - fy) * det;
        const float w10 = (1.0f - fx) * fy * det;
        const float w11 = fx * fy * det;
        dsum += det;

        const int i0 = yb * WI + xb;
        const int i1 = i0 + WI;
        { const float a0 = p0[i0], a1 = p0[i0 + 1], c0 = p0[i1], c1 = p0[i1 + 1];
          acc0 += a0 * w00 + a1 * w01 + c0 * w10 + c1 * w11; }
        { const float a0 = p1[i0], a1 = p1[i0 + 1], c0 = p1[i1], c1 = p1[i1 + 1];
          acc1 += a0 * w00 + a1 * w01 + c0 * w10 + c1 * w11; }
        { const float a0 = p2[i0], a1 = p2[i0 + 1], c0 = p2[i1], c1 = p2[i1 + 1];
          acc2 += a0 * w00 + a1 * w01 + c0 * w10 + c1 * w11; }
    };

    if (fits) {
        // ---- Async-stage bbox -> LDS planes via global_load_lds width 4.
        // Fixed trip count, fully unrolled, clamped index: all ~102 requests
        // go into flight back-to-back; one vmcnt(0) drain at the end. LDS
        // dest is wave-uniform base + lane*4 (HW rule); global src per-lane. ----
        const int npix  = nrows * ncols;
        const int niter = (npix + 63) >> 6;                      // <= NITER
        const unsigned mdiv = (1u << 22) / (unsigned)ncols + 1u; // i<4096: exact
        #pragma unroll
        for (int k = 0; k < NITER; ++k) {
            if (k < niter) {   // wave-uniform branch
                int i = k * 64 + lane;
                i = min(i, npix - 1);           // clamp: valid addr, dup write in pad
                const int r = (int)(((unsigned)i * mdiv) >> 22);
                const int c = i - r * ncols;
                const int g = (y_lo + r) * WI + (x_lo + c);
                __builtin_amdgcn_global_load_lds(AS1C(p0 + g), AS3(P0 + k * 64), 4, 0, 0);
                __builtin_amdgcn_global_load_lds(AS1C(p1 + g), AS3(P1 + k * 64), 4, 0, 0);
                __builtin_amdgcn_global_load_lds(AS1C(p2 + g), AS3(P2 + k * 64), 4, 0, 0);
            }
        }
        // Same wave produced and consumes: single vmcnt drain, no barrier.
        asm volatile("s_waitcnt vmcnt(0)" ::: "memory");
        __builtin_amdgcn_sched_barrier(0);

        // ---- This lane's 16 spp from LDS (fully unrolled, independent chains) ----
        sample_lds(jv0.x,  jv0.y);   sample_lds(jv1.x,  jv1.y);
        sample_lds(jv2.x,  jv2.y);   sample_lds(jv3.x,  jv3.y);
        sample_lds(jv4.x,  jv4.y);   sample_lds(jv5.x,  jv5.y);
        sample_lds(jv6.x,  jv6.y);   sample_lds(jv7.x,  jv7.y);
        sample_lds(jv8.x,  jv8.y);   sample_lds(jv9.x,  jv9.y);
        sample_lds(jv10.x, jv10.y);  sample_lds(jv11.x, jv11.y);
        sample_lds(jv12.x, jv12.y);  sample_lds(jv13.x, jv13.y);
        sample_lds(jv14.x, jv14.y);  sample_lds(jv15.x, jv15.y);
    } else {
        // ---- Fallback: direct global gathers (never taken at t=1) ----
        sample_glb(jv0.x,  jv0.y);   sample_glb(jv1.x,  jv1.y);
        sample_glb(jv2.x,  jv2.y);   sample_glb(jv3.x,  jv3.y);
        sample_glb(jv4.x,  jv4.y);   sample_glb(jv5.x,  jv5.y);
        sample_glb(jv6.x,  jv6.y);   sample_glb(jv7.x,  jv7.y);
        sample_glb(jv8.x,  jv8.y);   sample_glb(jv9.x,  jv9.y);
        sample_glb(jv10.x, jv10.y);  sample_glb(jv11.x, jv11.y);
        sample_glb(jv12.x, jv12.y);  sample_glb(jv13.x, jv13.y);
        sample_glb(jv14.x, jv14.y);  sample_glb(jv15.x, jv15.y);
    }

    // ---- 1 px per lane: no reduction, contiguous stores ----
    const float inv_d = 1.0f / dsum;
    const int pix = sy * SW + sx;
    const size_t ob = (size_t)b * CH * (SH * SW) + pix;
    out[ob]                 = acc0 * inv_d;
    out[ob + (SH * SW)]     = acc1 * inv_d;
    out[ob + 2 * (SH * SW)] = acc2 * inv_d;
}

extern "C" void kernel_launch(void* const* d_in, const int* in_sizes, int n_in,
                              void* d_out, int out_size, void* d_ws, size_t ws_size,
                              hipStream_t stream) {
    const float* img    = (const float*)d_in[0];
    const float* t      = (const float*)d_in[1];
    const float* jitter = (const float*)d_in[2];
    float* out          = (float*)d_out;

    // 4 batches x 32x32 tiles of 8x8 px = 4096 blocks, 64 threads (1 wave)
    hipLaunchKernelGGL(foveated_wave8, dim3(4096), dim3(NTHR), 0, stream,
                       img, t, jitter, out);
}